// Round 4
// baseline (980.806 us; speedup 1.0000x reference)
//
#include <hip/hip_runtime.h>

// GCN 2-layer: N=200000, E=6400000, 14 -> 16(relu) -> 2.
// Round 4: fix k_b2's 9% occupancy + 2.9 random lines/edge (R3: 597us).
//   - k_prep: xp[s] = dinv[s]*x[s] padded to 16 floats (64B line-aligned)
//     -> per-edge gather is ONE aligned cache line; no per-edge dinv load.
//   - 392 buckets x 512 nodes: LDS acc 512x17 = 34KB -> 4 blocks/CU (50% occ).
//   - 2-way edge-range split per bucket (grid 784) with partial aggx buffers
//     summed in k_node (no merge atomics). k_b3 splits 4-way (grid 1568).
//   - k_node stores h2bp = dinv*h2 so layer-2 gather is one aligned 8B load.
// Overflow fixups (capacity mean+16sigma) remain correctness no-ops.

constexpr int NN = 200000;
constexpr int NE = 6400000;
constexpr int IC = 14;
constexpr int HC = 16;
constexpr int OC = 2;

constexpr int NBK = 392;                   // buckets of 512 nodes (last one empty-ish)
constexpr int CAP = 18432;                 // mean 16384 + 16 sigma
constexpr int TILE = 6400;
constexpr int IPT = TILE / 256;            // 25
constexpr int NTILE = NE / TILE;           // 1000
constexpr int OVFCAP = 65536;
constexpr int NB = (NN + 255) / 256;       // 782

typedef unsigned long long ull;

__global__ void k_flag(const void* __restrict__ ei, int* __restrict__ flag) {
    if (blockIdx.x == 0 && threadIdx.x == 0) {
        const ull* p = (const ull*)ei;
        ull acc = 0ULL;
        for (int i = 0; i < 64; ++i) acc |= (p[i] >> 32);
        *flag = (acc == 0ULL) ? 1 : 0;  // 1 => int64 indices, 0 => int32
    }
}

__global__ void k_init(int* __restrict__ gcur) {
    int t = blockIdx.x * blockDim.x + threadIdx.x;
    if (t < NBK) gcur[t] = t * CAP;
    if (t == NBK) gcur[t] = 0;  // overflow counter
}

__device__ __forceinline__ int edge_src(const void* __restrict__ ei, int fl, int e) {
    if (fl) return (int)((const long long*)ei)[e];
    return ((const int*)ei)[e];
}
__device__ __forceinline__ int edge_dst(const void* __restrict__ ei, int fl, int e) {
    if (fl) return (int)((const long long*)ei)[NE + e];
    return ((const int*)ei)[NE + e];
}

__global__ __launch_bounds__(256) void k_binA(const void* __restrict__ ei,
                                              const int* __restrict__ flag,
                                              int* __restrict__ gcur,
                                              unsigned* __restrict__ binned,
                                              ull* __restrict__ ovf) {
    __shared__ int hist[NBK];       // counts, then staging cursors
    __shared__ int lofs[NBK];       // local exclusive offsets
    __shared__ int gofs[NBK];       // reserved global offsets
    __shared__ int scanbuf[256];
    __shared__ unsigned stage[TILE];
    __shared__ unsigned short sb[TILE];

    int t = threadIdx.x;
    int fl = *flag;
    int tile0 = blockIdx.x * TILE;

    if (t < NBK) hist[t] = 0;
    if (t + 256 < NBK) hist[t + 256] = 0;
    __syncthreads();

    int dsts[IPT];
#pragma unroll
    for (int k = 0; k < IPT; ++k) {
        int e = tile0 + k * 256 + t;
        int d = edge_dst(ei, fl, e);
        dsts[k] = d;
        atomicAdd(&hist[d >> 9], 1);
    }
    __syncthreads();

    // pairwise scan: 392 = 2*196 counts with a 256-wide Hillis-Steele
    int h0 = 0, h1 = 0, p = 0;
    if (t < NBK / 2) {
        h0 = hist[2 * t];
        h1 = hist[2 * t + 1];
        p = h0 + h1;
    }
    scanbuf[t] = p;
    __syncthreads();
#pragma unroll
    for (int off = 1; off < 256; off <<= 1) {
        int v = (t >= off) ? scanbuf[t - off] : 0;
        __syncthreads();
        scanbuf[t] += v;
        __syncthreads();
    }
    if (t < NBK / 2) {
        int excl = scanbuf[t] - p;
        lofs[2 * t] = excl;
        lofs[2 * t + 1] = excl + h0;
    }
    __syncthreads();
    if (t < NBK) {
        int c = hist[t];
        hist[t] = lofs[t];                  // staging cursor
        gofs[t] = atomicAdd(&gcur[t], c);   // reserve segment space
    }
    if (t + 256 < NBK) {
        int c = hist[t + 256];
        hist[t + 256] = lofs[t + 256];
        gofs[t + 256] = atomicAdd(&gcur[t + 256], c);
    }
    __syncthreads();

    // rank + stage
#pragma unroll
    for (int k = 0; k < IPT; ++k) {
        int e = tile0 + k * 256 + t;
        int s = edge_src(ei, fl, e);
        int d = dsts[k];
        int b = d >> 9;
        int pos = atomicAdd(&hist[b], 1);
        stage[pos] = (unsigned)(((d & 511) << 18) | s);
        sb[pos] = (unsigned short)b;
    }
    __syncthreads();

    // coalesced write-out: consecutive i within a bucket -> consecutive dest
    for (int i = t; i < TILE; i += 256) {
        int b = sb[i];
        unsigned pack = stage[i];
        int dest = gofs[b] + (i - lofs[b]);
        if (dest < (b + 1) * CAP) {
            binned[dest] = pack;
        } else {  // overflow (never in practice)
            int op = atomicAdd(&gcur[NBK], 1);
            if (op < OVFCAP) {
                int d = (b << 9) | (int)(pack >> 18);
                int s = (int)(pack & 0x3FFFF);
                ovf[op] = ((ull)d << 32) | (unsigned)s;
            }
        }
    }
}

// per-bucket degree count, 2-way split, partial outputs
__global__ __launch_bounds__(256) void k_b1(const int* __restrict__ gcur,
                                            const unsigned* __restrict__ binned,
                                            int* __restrict__ gcntp) {
    __shared__ int cnt[512];
    int b = blockIdx.x >> 1;
    int s = blockIdx.x & 1;
    int t = threadIdx.x;
    cnt[t] = 0;
    cnt[t + 256] = 0;
    __syncthreads();
    int base = b * CAP;
    int n = min(gcur[b], (b + 1) * CAP) - base;
    int mid = n >> 1;
    int beg = base + (s ? mid : 0);
    int end = base + (s ? n : mid);
    for (int i = beg + t; i < end; i += 256) {
        unsigned pack = binned[i];
        atomicAdd(&cnt[pack >> 18], 1);
    }
    __syncthreads();
    int* out = gcntp + (size_t)s * NN;
    for (int i = t; i < 512; i += 256) {
        int g = (b << 9) + i;
        if (g < NN) out[g] = cnt[i];
    }
}

__global__ void k_ovf1(const int* __restrict__ gcur, const ull* __restrict__ ovf,
                       int* __restrict__ gcntp) {
    int nov = min(gcur[NBK], OVFCAP);
    for (int i = blockIdx.x * blockDim.x + threadIdx.x; i < nov; i += gridDim.x * blockDim.x) {
        int d = (int)(ovf[i] >> 32);
        atomicAdd(&gcntp[d], 1);
    }
}

__global__ void k_dinv(const int* __restrict__ gcntp, float* __restrict__ dinv) {
    int i = blockIdx.x * blockDim.x + threadIdx.x;
    if (i < NN) dinv[i] = rsqrtf((float)(gcntp[i] + gcntp[NN + i]) + 1.0f);
}

// xp[s] = dinv[s]*x[s], padded to 16 floats (64B aligned rows)
__global__ void k_prep(const float* __restrict__ x, const float* __restrict__ dinv,
                       float* __restrict__ xp) {
    int i = blockIdx.x * blockDim.x + threadIdx.x;
    if (i >= NN * 16) return;
    int node = i >> 4;
    int c = i & 15;
    xp[i] = (c < IC) ? dinv[node] * x[node * IC + c] : 0.0f;
}

// layer-1 aggregation: one aligned 64B line per edge, LDS acc 512x17
__global__ __launch_bounds__(256) void k_b2(const int* __restrict__ gcur,
                                            const unsigned* __restrict__ binned,
                                            const float* __restrict__ xp,
                                            float* __restrict__ aggxp) {
    __shared__ float acc[512 * 17];  // 34816 B -> 4 blocks/CU
    int b = blockIdx.x >> 1;
    int s = blockIdx.x & 1;
    int t = threadIdx.x;
    for (int i = t; i < 512 * 17; i += 256) acc[i] = 0.0f;
    __syncthreads();
    int base = b * CAP;
    int n = min(gcur[b], (b + 1) * CAP) - base;
    int mid = n >> 1;
    int beg = base + (s ? mid : 0);
    int end = base + (s ? n : mid);
    for (int i = beg + t; i < end; i += 256) {
        unsigned pack = binned[i];
        int src = (int)(pack & 0x3FFFF);
        int nl = (int)(pack >> 18);
        const float4* row = (const float4*)(xp + (size_t)src * 16);
        float* a = &acc[nl * 17];
#pragma unroll
        for (int q = 0; q < 4; ++q) {
            float4 v = row[q];
            atomicAdd(&a[4 * q + 0], v.x);
            atomicAdd(&a[4 * q + 1], v.y);
            atomicAdd(&a[4 * q + 2], v.z);
            atomicAdd(&a[4 * q + 3], v.w);  // channels 14,15 are zero pad
        }
    }
    __syncthreads();
    float* out = aggxp + (size_t)s * NN * 16;
    for (int i = t; i < 512 * 16; i += 256) {
        int nl = i >> 4;
        int c = i & 15;
        int g = (b << 9) + nl;
        if (g < NN) out[(size_t)g * 16 + c] = acc[nl * 17 + c];
    }
}

__global__ void k_ovf2(const int* __restrict__ gcur, const ull* __restrict__ ovf,
                       const float* __restrict__ dinv, const float* __restrict__ x,
                       float* __restrict__ aggxp) {
    int nov = min(gcur[NBK], OVFCAP);
    for (int i = blockIdx.x * blockDim.x + threadIdx.x; i < nov; i += gridDim.x * blockDim.x) {
        int d = (int)(ovf[i] >> 32);
        int s = (int)(ovf[i] & 0xFFFFFFFFu);
        float w = dinv[s];
        for (int c = 0; c < IC; ++c)
            atomicAdd(&aggxp[(size_t)d * 16 + c], w * x[(size_t)s * IC + c]);
    }
}

__global__ void k_node(const float* __restrict__ x, const float* __restrict__ dinv,
                       const float* __restrict__ aggxp, const float* __restrict__ W1,
                       const float* __restrict__ b1, const float* __restrict__ W2,
                       const float* __restrict__ b2, float* __restrict__ h2bp,
                       float* __restrict__ out) {
    __shared__ float sW1[IC * HC];
    __shared__ float sb1[HC];
    __shared__ float sW2[HC * OC];
    __shared__ float sb2[OC];
    int t = threadIdx.x;
    if (t < IC * HC) sW1[t] = W1[t];
    if (t < HC) sb1[t] = b1[t];
    if (t < HC * OC) sW2[t] = W2[t];
    if (t < OC) sb2[t] = b2[t];
    __syncthreads();

    int i = blockIdx.x * blockDim.x + t;
    if (i >= NN) return;

    float dv = dinv[i];
    float dv2 = dv * dv;
    const float* a0 = aggxp + (size_t)i * 16;
    const float* a1 = aggxp + (size_t)(NN + i) * 16;
    float tt[IC];
#pragma unroll
    for (int c = 0; c < IC; ++c)
        tt[c] = dv * (a0[c] + a1[c]) + dv2 * x[(size_t)i * IC + c];

    float r[HC];
#pragma unroll
    for (int f = 0; f < HC; ++f) {
        float acc = sb1[f];
#pragma unroll
        for (int c = 0; c < IC; ++c) acc = fmaf(tt[c], sW1[c * HC + f], acc);
        r[f] = fmaxf(acc, 0.0f);
    }

    float o0 = 0.0f, o1 = 0.0f;
#pragma unroll
    for (int f = 0; f < HC; ++f) {
        o0 = fmaf(r[f], sW2[f * OC + 0], o0);
        o1 = fmaf(r[f], sW2[f * OC + 1], o1);
    }
    // prescale by dinv[i] so layer-2 edge gather needs no dinv[src] load
    h2bp[(size_t)i * OC + 0] = o0 * dv;
    h2bp[(size_t)i * OC + 1] = o1 * dv;
    out[(size_t)i * OC + 0] = o0 * dv2 + sb2[0];
    out[(size_t)i * OC + 1] = o1 * dv2 + sb2[1];
}

// layer-2 aggregation: one aligned 8B load per edge, 4-way split, 6KB LDS
__global__ __launch_bounds__(256) void k_b3(const int* __restrict__ gcur,
                                            const unsigned* __restrict__ binned,
                                            const float* __restrict__ h2bp,
                                            float* __restrict__ h2p) {
    __shared__ float acc2[512 * 3];
    int b = blockIdx.x >> 2;
    int s = blockIdx.x & 3;
    int t = threadIdx.x;
    for (int i = t; i < 512 * 3; i += 256) acc2[i] = 0.0f;
    __syncthreads();
    int base = b * CAP;
    int n = min(gcur[b], (b + 1) * CAP) - base;
    int beg = base + (n * s) / 4;
    int end = base + (n * (s + 1)) / 4;
    for (int i = beg + t; i < end; i += 256) {
        unsigned pack = binned[i];
        int src = (int)(pack & 0x3FFFF);
        int nl = (int)(pack >> 18);
        float2 h = *(const float2*)(h2bp + (size_t)src * OC);
        atomicAdd(&acc2[nl * 3 + 0], h.x);
        atomicAdd(&acc2[nl * 3 + 1], h.y);
    }
    __syncthreads();
    float* out = h2p + (size_t)s * NN * OC;
    for (int i = t; i < 512; i += 256) {
        int g = (b << 9) + i;
        if (g < NN) {
            out[(size_t)g * OC + 0] = acc2[i * 3 + 0];
            out[(size_t)g * OC + 1] = acc2[i * 3 + 1];
        }
    }
}

__global__ void k_ovf3(const int* __restrict__ gcur, const ull* __restrict__ ovf,
                       const float* __restrict__ h2bp, float* __restrict__ h2p) {
    int nov = min(gcur[NBK], OVFCAP);
    for (int i = blockIdx.x * blockDim.x + threadIdx.x; i < nov; i += gridDim.x * blockDim.x) {
        int d = (int)(ovf[i] >> 32);
        int s = (int)(ovf[i] & 0xFFFFFFFFu);
        atomicAdd(&h2p[(size_t)d * OC + 0], h2bp[(size_t)s * OC + 0]);
        atomicAdd(&h2p[(size_t)d * OC + 1], h2bp[(size_t)s * OC + 1]);
    }
}

__global__ void k_merge(const float* __restrict__ dinv, const float* __restrict__ h2p,
                        float* __restrict__ out) {
    int i = blockIdx.x * blockDim.x + threadIdx.x;
    if (i >= NN * OC) return;
    int node = i >> 1;
    float sum = h2p[i] + h2p[(size_t)NN * OC + i] + h2p[(size_t)2 * NN * OC + i] +
                h2p[(size_t)3 * NN * OC + i];
    out[i] += dinv[node] * sum;
}

extern "C" void kernel_launch(void* const* d_in, const int* in_sizes, int n_in,
                              void* d_out, int out_size, void* d_ws, size_t ws_size,
                              hipStream_t stream) {
    const float* x = (const float*)d_in[0];
    const void* ei = d_in[1];
    // d_in[2] = edge_attr (unused)
    const float* W1 = (const float*)d_in[3];
    const float* b1 = (const float*)d_in[4];
    const float* W2 = (const float*)d_in[5];
    const float* b2 = (const float*)d_in[6];
    float* out = (float*)d_out;

    ull* ovf = (ull*)d_ws;                              // OVFCAP
    int* gcur = (int*)(ovf + OVFCAP);                   // NBK+1 -> pad 512
    int* flag = gcur + 512;                             // 4
    int* gcntp = flag + 4;                              // 2*NN
    float* dinv = (float*)(gcntp + 2 * NN);             // NN
    float* xp = dinv + NN;                              // NN*16
    float* aggxp = xp + (size_t)NN * 16;                // 2*NN*16
    float* h2bp = aggxp + (size_t)2 * NN * 16;          // NN*OC
    float* h2p = h2bp + (size_t)NN * OC;                // 4*NN*OC
    unsigned* binned = (unsigned*)(h2p + (size_t)4 * NN * OC);  // NBK*CAP

    k_flag<<<1, 64, 0, stream>>>(ei, flag);
    k_init<<<2, 256, 0, stream>>>(gcur);
    k_binA<<<NTILE, 256, 0, stream>>>(ei, flag, gcur, binned, ovf);
    k_b1<<<NBK * 2, 256, 0, stream>>>(gcur, binned, gcntp);
    k_ovf1<<<8, 256, 0, stream>>>(gcur, ovf, gcntp);
    k_dinv<<<NB, 256, 0, stream>>>(gcntp, dinv);
    k_prep<<<(NN * 16 + 255) / 256, 256, 0, stream>>>(x, dinv, xp);
    k_b2<<<NBK * 2, 256, 0, stream>>>(gcur, binned, xp, aggxp);
    k_ovf2<<<8, 256, 0, stream>>>(gcur, ovf, dinv, x, aggxp);
    k_node<<<NB, 256, 0, stream>>>(x, dinv, aggxp, W1, b1, W2, b2, h2bp, out);
    k_b3<<<NBK * 4, 256, 0, stream>>>(gcur, binned, h2bp, h2p);
    k_ovf3<<<8, 256, 0, stream>>>(gcur, ovf, h2bp, h2p);
    k_merge<<<(NN * OC + 255) / 256, 256, 0, stream>>>(dinv, h2p, out);
}

// Round 5
// 553.468 us; speedup vs baseline: 1.7721x; 1.7721x over previous
//
#include <hip/hip_runtime.h>

// GCN 2-layer: N=200000, E=6400000, 14 -> 16(relu) -> 2.
// Round 5: R3/R4's k_b2 was LDS-atomic-issue bound (16 ds_add/edge x ~4cyc x
// 25k edges/CU = 667us ~= measured 673us). Replace LDS-atomic aggregation with
// bucket-local counting sort by dst (k_sort; histogram doubles as degree) and
// thread-per-dst REGISTER accumulation over the dst-sorted CSR:
//   k_binA:  bin edges by dst>>9 into 392 L2-sized segments (unchanged).
//   k_sort:  per-bucket counting sort -> csr (src only), gcnt, rsg. Scattered
//            4B writes stay inside a 72KB L2-resident segment (no amplification).
//   k_agg1n: per dst node: acc16 += xp[src] rows (4 same-line float4 loads +
//            16 fma per edge, zero LDS ops) fused with the whole node MLP
//            (tt = dinv*(acc + xp[i] + aggovf[i]); relu(W1)+W2) -> h2bp, selfout.
//   k_agg2:  per dst node: out = selfout + dinv * sum h2bp[src] (8B L2-resident).
// Overflow path (never taken): ovf list -> gcnt/aggovf/out fixups.

constexpr int NN = 200000;
constexpr int NE = 6400000;
constexpr int IC = 14;
constexpr int HC = 16;
constexpr int OC = 2;

constexpr int NBK = 392;                   // buckets of 512 dst nodes
constexpr int CAP = 18432;                 // mean 16328 + ~16 sigma
constexpr int TILE = 6400;
constexpr int IPT = TILE / 256;            // 25
constexpr int NTILE = NE / TILE;           // 1000
constexpr int OVFCAP = 65536;
constexpr int NB = (NN + 255) / 256;       // 782

typedef unsigned long long ull;

__global__ void k_flag(const void* __restrict__ ei, int* __restrict__ flag) {
    if (blockIdx.x == 0 && threadIdx.x == 0) {
        const ull* p = (const ull*)ei;
        ull acc = 0ULL;
        for (int i = 0; i < 64; ++i) acc |= (p[i] >> 32);
        *flag = (acc == 0ULL) ? 1 : 0;  // 1 => int64 indices, 0 => int32
    }
}

__global__ void k_init(int* __restrict__ gcur) {
    int t = blockIdx.x * blockDim.x + threadIdx.x;
    if (t < NBK) gcur[t] = t * CAP;
    if (t == NBK) gcur[t] = 0;  // overflow counter
}

__global__ void k_zero(float* __restrict__ aggovf) {
    int i = blockIdx.x * blockDim.x + threadIdx.x;
    if (i < NN * 16) aggovf[i] = 0.0f;
}

__device__ __forceinline__ int edge_src(const void* __restrict__ ei, int fl, int e) {
    if (fl) return (int)((const long long*)ei)[e];
    return ((const int*)ei)[e];
}
__device__ __forceinline__ int edge_dst(const void* __restrict__ ei, int fl, int e) {
    if (fl) return (int)((const long long*)ei)[NE + e];
    return ((const int*)ei)[NE + e];
}

__global__ __launch_bounds__(256) void k_binA(const void* __restrict__ ei,
                                              const int* __restrict__ flag,
                                              int* __restrict__ gcur,
                                              unsigned* __restrict__ binned,
                                              ull* __restrict__ ovf) {
    __shared__ int hist[NBK];       // counts, then staging cursors
    __shared__ int lofs[NBK];       // local exclusive offsets
    __shared__ int gofs[NBK];       // reserved global offsets
    __shared__ int scanbuf[256];
    __shared__ unsigned stage[TILE];
    __shared__ unsigned short sb[TILE];

    int t = threadIdx.x;
    int fl = *flag;
    int tile0 = blockIdx.x * TILE;

    if (t < NBK) hist[t] = 0;
    if (t + 256 < NBK) hist[t + 256] = 0;
    __syncthreads();

    int dsts[IPT];
#pragma unroll
    for (int k = 0; k < IPT; ++k) {
        int e = tile0 + k * 256 + t;
        int d = edge_dst(ei, fl, e);
        dsts[k] = d;
        atomicAdd(&hist[d >> 9], 1);
    }
    __syncthreads();

    // pairwise scan: 392 = 2*196 counts with a 256-wide Hillis-Steele
    int h0 = 0, h1 = 0, p = 0;
    if (t < NBK / 2) {
        h0 = hist[2 * t];
        h1 = hist[2 * t + 1];
        p = h0 + h1;
    }
    scanbuf[t] = p;
    __syncthreads();
#pragma unroll
    for (int off = 1; off < 256; off <<= 1) {
        int v = (t >= off) ? scanbuf[t - off] : 0;
        __syncthreads();
        scanbuf[t] += v;
        __syncthreads();
    }
    if (t < NBK / 2) {
        int excl = scanbuf[t] - p;
        lofs[2 * t] = excl;
        lofs[2 * t + 1] = excl + h0;
    }
    __syncthreads();
    if (t < NBK) {
        int c = hist[t];
        hist[t] = lofs[t];                  // staging cursor
        gofs[t] = atomicAdd(&gcur[t], c);   // reserve segment space
    }
    if (t + 256 < NBK) {
        int c = hist[t + 256];
        hist[t + 256] = lofs[t + 256];
        gofs[t + 256] = atomicAdd(&gcur[t + 256], c);
    }
    __syncthreads();

    // rank + stage
#pragma unroll
    for (int k = 0; k < IPT; ++k) {
        int e = tile0 + k * 256 + t;
        int s = edge_src(ei, fl, e);
        int d = dsts[k];
        int b = d >> 9;
        int pos = atomicAdd(&hist[b], 1);
        stage[pos] = (unsigned)(((d & 511) << 18) | s);
        sb[pos] = (unsigned short)b;
    }
    __syncthreads();

    // coalesced write-out: consecutive i within a bucket -> consecutive dest
    for (int i = t; i < TILE; i += 256) {
        int b = sb[i];
        unsigned pack = stage[i];
        int dest = gofs[b] + (i - lofs[b]);
        if (dest < (b + 1) * CAP) {
            binned[dest] = pack;
        } else {  // overflow (never in practice)
            int op = atomicAdd(&gcur[NBK], 1);
            if (op < OVFCAP) {
                int d = (b << 9) | (int)(pack >> 18);
                int s = (int)(pack & 0x3FFFF);
                ovf[op] = ((ull)d << 32) | (unsigned)s;
            }
        }
    }
}

// bucket-local counting sort by dst; histogram doubles as degree output
__global__ __launch_bounds__(512) void k_sort(const int* __restrict__ gcur,
                                              const unsigned* __restrict__ binned,
                                              unsigned* __restrict__ csr,
                                              int* __restrict__ gcnt,
                                              int* __restrict__ rsg) {
    __shared__ int cnt[512];
    __shared__ int sh[512];
    __shared__ int cur[512];
    int b = blockIdx.x;
    int t = threadIdx.x;
    cnt[t] = 0;
    __syncthreads();
    int base = b * CAP;
    int n = min(gcur[b], (b + 1) * CAP) - base;
    for (int i = t; i < n; i += 512)
        atomicAdd(&cnt[binned[base + i] >> 18], 1);
    __syncthreads();
    int c = cnt[t];
    sh[t] = c;
    __syncthreads();
#pragma unroll
    for (int off = 1; off < 512; off <<= 1) {
        int v = (t >= off) ? sh[t - off] : 0;
        __syncthreads();
        sh[t] += v;
        __syncthreads();
    }
    int excl = sh[t] - c;
    cur[t] = base + excl;
    int g = (b << 9) + t;
    if (g < NN) {
        gcnt[g] = c;
        rsg[g] = base + excl;
    }
    __syncthreads();
    for (int i = t; i < n; i += 512) {
        unsigned pack = binned[base + i];
        int nl = (int)(pack >> 18);
        int pos = atomicAdd(&cur[nl], 1);
        csr[pos] = pack & 0x3FFFF;  // src only; dst implied by rsg ranges
    }
}

__global__ void k_ovf1(const int* __restrict__ gcur, const ull* __restrict__ ovf,
                       int* __restrict__ gcnt) {
    int nov = min(gcur[NBK], OVFCAP);
    for (int i = blockIdx.x * blockDim.x + threadIdx.x; i < nov; i += gridDim.x * blockDim.x) {
        int d = (int)(ovf[i] >> 32);
        atomicAdd(&gcnt[d], 1);
    }
}

__global__ void k_dinv(const int* __restrict__ gcnt, float* __restrict__ dinv) {
    int i = blockIdx.x * blockDim.x + threadIdx.x;
    if (i < NN) dinv[i] = rsqrtf((float)gcnt[i] + 1.0f);
}

// xp[s] = dinv[s]*x[s], padded to 16 floats (one aligned 64B line per row)
__global__ void k_prep(const float* __restrict__ x, const float* __restrict__ dinv,
                       float* __restrict__ xp) {
    int i = blockIdx.x * blockDim.x + threadIdx.x;
    if (i >= NN * 16) return;
    int node = i >> 4;
    int c = i & 15;
    xp[i] = (c < IC) ? dinv[node] * x[node * IC + c] : 0.0f;
}

__global__ void k_ovf2(const int* __restrict__ gcur, const ull* __restrict__ ovf,
                       const float* __restrict__ xp, float* __restrict__ aggovf) {
    int nov = min(gcur[NBK], OVFCAP);
    for (int i = blockIdx.x * blockDim.x + threadIdx.x; i < nov; i += gridDim.x * blockDim.x) {
        int d = (int)(ovf[i] >> 32);
        int s = (int)(ovf[i] & 0xFFFFFFFFu);
        for (int c = 0; c < 16; ++c)
            atomicAdd(&aggovf[(size_t)d * 16 + c], xp[(size_t)s * 16 + c]);
    }
}

// layer-1 aggregation (register acc over dst-sorted CSR) fused with node MLP.
// dinv^2*x[i] == dinv*xp[i], so the self loop is just "add own xp row".
__global__ __launch_bounds__(256) void k_agg1n(const int* __restrict__ rsg,
                                               const int* __restrict__ gcnt,
                                               const unsigned* __restrict__ csr,
                                               const float* __restrict__ xp,
                                               const float* __restrict__ aggovf,
                                               const float* __restrict__ dinv,
                                               const float* __restrict__ W1,
                                               const float* __restrict__ b1,
                                               const float* __restrict__ W2,
                                               const float* __restrict__ b2,
                                               float2* __restrict__ h2bp,
                                               float2* __restrict__ selfout) {
    __shared__ float sW1[IC * HC];
    __shared__ float sb1[HC];
    __shared__ float sW2[HC * OC];
    __shared__ float sb2[OC];
    int t = threadIdx.x;
    if (t < IC * HC) sW1[t] = W1[t];
    if (t < HC) sb1[t] = b1[t];
    if (t < HC * OC) sW2[t] = W2[t];
    if (t < OC) sb2[t] = b2[t];
    __syncthreads();

    int i = blockIdx.x * 256 + t;
    if (i >= NN) return;

    int beg = rsg[i];
    int end = beg + gcnt[i];
    float acc[16];
#pragma unroll
    for (int c = 0; c < 16; ++c) acc[c] = 0.0f;

    int j = beg;
    for (; j + 1 < end; j += 2) {  // unroll 2: two random lines in flight
        int s0 = csr[j];
        int s1 = csr[j + 1];
        const float4* r0 = (const float4*)(xp + (size_t)s0 * 16);
        const float4* r1 = (const float4*)(xp + (size_t)s1 * 16);
#pragma unroll
        for (int q = 0; q < 4; ++q) {
            float4 u = r0[q];
            float4 v = r1[q];
            acc[4 * q + 0] += u.x + v.x;
            acc[4 * q + 1] += u.y + v.y;
            acc[4 * q + 2] += u.z + v.z;
            acc[4 * q + 3] += u.w + v.w;
        }
    }
    if (j < end) {
        const float4* r0 = (const float4*)(xp + (size_t)csr[j] * 16);
#pragma unroll
        for (int q = 0; q < 4; ++q) {
            float4 u = r0[q];
            acc[4 * q + 0] += u.x;
            acc[4 * q + 1] += u.y;
            acc[4 * q + 2] += u.z;
            acc[4 * q + 3] += u.w;
        }
    }

    float dv = dinv[i];
    const float* sp = xp + (size_t)i * 16;
    const float* op = aggovf + (size_t)i * 16;
    float tt[IC];
#pragma unroll
    for (int c = 0; c < IC; ++c) tt[c] = dv * (acc[c] + sp[c] + op[c]);

    float r[HC];
#pragma unroll
    for (int f = 0; f < HC; ++f) {
        float a = sb1[f];
#pragma unroll
        for (int c = 0; c < IC; ++c) a = fmaf(tt[c], sW1[c * HC + f], a);
        r[f] = fmaxf(a, 0.0f);
    }

    float o0 = 0.0f, o1 = 0.0f;
#pragma unroll
    for (int f = 0; f < HC; ++f) {
        o0 = fmaf(r[f], sW2[f * OC + 0], o0);
        o1 = fmaf(r[f], sW2[f * OC + 1], o1);
    }
    h2bp[i] = make_float2(o0 * dv, o1 * dv);                        // dinv-prescaled
    selfout[i] = make_float2(o0 * dv * dv + sb2[0], o1 * dv * dv + sb2[1]);
}

// layer-2: out[i] = selfout[i] + dinv[i] * sum h2bp[src]; h2bp (1.6MB) is L2-resident
__global__ __launch_bounds__(256) void k_agg2(const int* __restrict__ rsg,
                                              const int* __restrict__ gcnt,
                                              const unsigned* __restrict__ csr,
                                              const float* __restrict__ dinv,
                                              const float2* __restrict__ h2bp,
                                              const float2* __restrict__ selfout,
                                              float2* __restrict__ out) {
    int i = blockIdx.x * 256 + threadIdx.x;
    if (i >= NN) return;
    int beg = rsg[i];
    int end = beg + gcnt[i];
    float ax = 0.0f, ay = 0.0f;
    int j = beg;
    for (; j + 1 < end; j += 2) {
        float2 h0 = h2bp[csr[j]];
        float2 h1 = h2bp[csr[j + 1]];
        ax += h0.x + h1.x;
        ay += h0.y + h1.y;
    }
    if (j < end) {
        float2 h = h2bp[csr[j]];
        ax += h.x;
        ay += h.y;
    }
    float dv = dinv[i];
    float2 so = selfout[i];
    out[i] = make_float2(so.x + dv * ax, so.y + dv * ay);
}

__global__ void k_ovf3(const int* __restrict__ gcur, const ull* __restrict__ ovf,
                       const float* __restrict__ dinv, const float2* __restrict__ h2bp,
                       float* __restrict__ out) {
    int nov = min(gcur[NBK], OVFCAP);
    for (int i = blockIdx.x * blockDim.x + threadIdx.x; i < nov; i += gridDim.x * blockDim.x) {
        int d = (int)(ovf[i] >> 32);
        int s = (int)(ovf[i] & 0xFFFFFFFFu);
        float2 h = h2bp[s];
        atomicAdd(&out[(size_t)d * OC + 0], dinv[d] * h.x);
        atomicAdd(&out[(size_t)d * OC + 1], dinv[d] * h.y);
    }
}

extern "C" void kernel_launch(void* const* d_in, const int* in_sizes, int n_in,
                              void* d_out, int out_size, void* d_ws, size_t ws_size,
                              hipStream_t stream) {
    const float* x = (const float*)d_in[0];
    const void* ei = d_in[1];
    // d_in[2] = edge_attr (unused)
    const float* W1 = (const float*)d_in[3];
    const float* b1 = (const float*)d_in[4];
    const float* W2 = (const float*)d_in[5];
    const float* b2 = (const float*)d_in[6];
    float* out = (float*)d_out;

    ull* ovf = (ull*)d_ws;                              // OVFCAP
    int* gcur = (int*)(ovf + OVFCAP);                   // NBK+1 -> pad 512
    int* flag = gcur + 512;                             // 4
    int* gcnt = flag + 4;                               // NN
    int* rsg = gcnt + NN;                               // NN
    float* dinv = (float*)(rsg + NN);                   // NN
    float* xp = dinv + NN;                              // NN*16
    float* aggovf = xp + (size_t)NN * 16;               // NN*16
    float2* h2bp = (float2*)(aggovf + (size_t)NN * 16); // NN
    float2* selfout = h2bp + NN;                        // NN
    unsigned* binned = (unsigned*)(selfout + NN);       // NBK*CAP
    unsigned* csr = binned + (size_t)NBK * CAP;         // NBK*CAP

    k_flag<<<1, 64, 0, stream>>>(ei, flag);
    k_init<<<2, 256, 0, stream>>>(gcur);
    k_zero<<<(NN * 16 + 255) / 256, 256, 0, stream>>>(aggovf);
    k_binA<<<NTILE, 256, 0, stream>>>(ei, flag, gcur, binned, ovf);
    k_sort<<<NBK, 512, 0, stream>>>(gcur, binned, csr, gcnt, rsg);
    k_ovf1<<<8, 256, 0, stream>>>(gcur, ovf, gcnt);
    k_dinv<<<NB, 256, 0, stream>>>(gcnt, dinv);
    k_prep<<<(NN * 16 + 255) / 256, 256, 0, stream>>>(x, dinv, xp);
    k_ovf2<<<8, 256, 0, stream>>>(gcur, ovf, xp, aggovf);
    k_agg1n<<<NB, 256, 0, stream>>>(rsg, gcnt, csr, xp, aggovf, dinv, W1, b1, W2, b2,
                                    h2bp, selfout);
    k_agg2<<<NB, 256, 0, stream>>>(rsg, gcnt, csr, dinv, h2bp, selfout, (float2*)out);
    k_ovf3<<<8, 256, 0, stream>>>(gcur, ovf, dinv, h2bp, out);
}

// Round 6
// 510.843 us; speedup vs baseline: 1.9200x; 1.0834x over previous
//
#include <hip/hip_runtime.h>

// GCN 2-layer: N=200000, E=6400000, 14 -> 16(relu) -> 2.
// Round 6: k_agg1n was L1-request-rate bound (4 uncoalesced float4 instrs/edge,
// 64 line-requests per wave-instr, 20cyc/edge). Now 4 lanes cooperate per dst
// node: lane q loads chunk q of the 64B-aligned xp row -> 1 coalesced 64B
// request/edge, 1 instr/edge. Partial sums cross lanes via 5KB LDS (stride 17),
// then 64 threads/block run the fused node MLP. k_binA drops its 2nd LDS atomic
// per edge by capturing rank from the histogram atomic (rank<<18|dst in regs).
// Pipeline: binA (bin by dst>>9) -> sort (bucket counting sort, degrees free)
//           -> dinv/prep -> agg1n (reg-acc gather + MLP) -> agg2.

constexpr int NN = 200000;
constexpr int NE = 6400000;
constexpr int IC = 14;
constexpr int HC = 16;
constexpr int OC = 2;

constexpr int NBK = 392;                   // buckets of 512 dst nodes
constexpr int CAP = 18432;                 // mean 16328 + ~16 sigma
constexpr int TILE = 6400;
constexpr int IPT = TILE / 256;            // 25
constexpr int NTILE = NE / TILE;           // 1000
constexpr int OVFCAP = 65536;
constexpr int NB = (NN + 255) / 256;       // 782

typedef unsigned long long ull;

__global__ void k_flag(const void* __restrict__ ei, int* __restrict__ flag) {
    if (blockIdx.x == 0 && threadIdx.x == 0) {
        const ull* p = (const ull*)ei;
        ull acc = 0ULL;
        for (int i = 0; i < 64; ++i) acc |= (p[i] >> 32);
        *flag = (acc == 0ULL) ? 1 : 0;  // 1 => int64 indices, 0 => int32
    }
}

__global__ void k_init(int* __restrict__ gcur) {
    int t = blockIdx.x * blockDim.x + threadIdx.x;
    if (t < NBK) gcur[t] = t * CAP;
    if (t == NBK) gcur[t] = 0;  // overflow counter
}

__device__ __forceinline__ int edge_src(const void* __restrict__ ei, int fl, int e) {
    if (fl) return (int)((const long long*)ei)[e];
    return ((const int*)ei)[e];
}
__device__ __forceinline__ int edge_dst(const void* __restrict__ ei, int fl, int e) {
    if (fl) return (int)((const long long*)ei)[NE + e];
    return ((const int*)ei)[NE + e];
}

__global__ __launch_bounds__(256) void k_binA(const void* __restrict__ ei,
                                              const int* __restrict__ flag,
                                              int* __restrict__ gcur,
                                              unsigned* __restrict__ binned,
                                              ull* __restrict__ ovf) {
    __shared__ int hist[NBK];       // per-bucket counts
    __shared__ int lofs[NBK];       // local exclusive offsets
    __shared__ int gofs[NBK];       // reserved global offsets
    __shared__ int scanbuf[256];
    __shared__ unsigned stage[TILE];
    __shared__ unsigned short sb[TILE];

    int t = threadIdx.x;
    int fl = *flag;
    int tile0 = blockIdx.x * TILE;

    if (t < NBK) hist[t] = 0;
    if (t + 256 < NBK) hist[t + 256] = 0;
    __syncthreads();

    // load dst; histogram atomic doubles as rank capture: dr = rank<<18 | dst
    int dr[IPT];
#pragma unroll
    for (int k = 0; k < IPT; ++k) {
        int e = tile0 + k * 256 + t;
        int d = edge_dst(ei, fl, e);
        int r = atomicAdd(&hist[d >> 9], 1);
        dr[k] = (r << 18) | d;
    }
    __syncthreads();

    // pairwise scan: 392 = 2*196 counts with a 256-wide Hillis-Steele
    int h0 = 0, h1 = 0, p = 0;
    if (t < NBK / 2) {
        h0 = hist[2 * t];
        h1 = hist[2 * t + 1];
        p = h0 + h1;
    }
    scanbuf[t] = p;
    __syncthreads();
#pragma unroll
    for (int off = 1; off < 256; off <<= 1) {
        int v = (t >= off) ? scanbuf[t - off] : 0;
        __syncthreads();
        scanbuf[t] += v;
        __syncthreads();
    }
    if (t < NBK / 2) {
        int excl = scanbuf[t] - p;
        lofs[2 * t] = excl;
        lofs[2 * t + 1] = excl + h0;
    }
    __syncthreads();
    if (t < NBK) gofs[t] = atomicAdd(&gcur[t], hist[t]);
    if (t + 256 < NBK) gofs[t + 256] = atomicAdd(&gcur[t + 256], hist[t + 256]);
    __syncthreads();

    // stage at lofs[bucket] + rank (no second atomic)
#pragma unroll
    for (int k = 0; k < IPT; ++k) {
        int e = tile0 + k * 256 + t;
        int s = edge_src(ei, fl, e);
        int d = dr[k] & 0x3FFFF;
        int r = ((unsigned)dr[k]) >> 18;
        int b = d >> 9;
        int pos = lofs[b] + r;
        stage[pos] = (unsigned)(((d & 511) << 18) | s);
        sb[pos] = (unsigned short)b;
    }
    __syncthreads();

    // coalesced write-out: consecutive i within a bucket -> consecutive dest
    for (int i = t; i < TILE; i += 256) {
        int b = sb[i];
        unsigned pack = stage[i];
        int dest = gofs[b] + (i - lofs[b]);
        if (dest < (b + 1) * CAP) {
            binned[dest] = pack;
        } else {  // overflow (never in practice)
            int op = atomicAdd(&gcur[NBK], 1);
            if (op < OVFCAP) {
                int d = (b << 9) | (int)(pack >> 18);
                int s = (int)(pack & 0x3FFFF);
                ovf[op] = ((ull)d << 32) | (unsigned)s;
            }
        }
    }
}

// bucket-local counting sort by dst; histogram doubles as degree output
__global__ __launch_bounds__(512) void k_sort(const int* __restrict__ gcur,
                                              const unsigned* __restrict__ binned,
                                              unsigned* __restrict__ csr,
                                              int* __restrict__ gcnt,
                                              int* __restrict__ rsg) {
    __shared__ int cnt[512];
    __shared__ int sh[512];
    __shared__ int cur[512];
    int b = blockIdx.x;
    int t = threadIdx.x;
    cnt[t] = 0;
    __syncthreads();
    int base = b * CAP;
    int n = min(gcur[b], (b + 1) * CAP) - base;
    for (int i = t; i < n; i += 512)
        atomicAdd(&cnt[binned[base + i] >> 18], 1);
    __syncthreads();
    int c = cnt[t];
    sh[t] = c;
    __syncthreads();
#pragma unroll
    for (int off = 1; off < 512; off <<= 1) {
        int v = (t >= off) ? sh[t - off] : 0;
        __syncthreads();
        sh[t] += v;
        __syncthreads();
    }
    int excl = sh[t] - c;
    cur[t] = base + excl;
    int g = (b << 9) + t;
    if (g < NN) {
        gcnt[g] = c;
        rsg[g] = base + excl;
    }
    __syncthreads();
    for (int i = t; i < n; i += 512) {
        unsigned pack = binned[base + i];
        int nl = (int)(pack >> 18);
        int pos = atomicAdd(&cur[nl], 1);
        csr[pos] = pack & 0x3FFFF;  // src only; dst implied by rsg ranges
    }
}

__global__ void k_ovf1(const int* __restrict__ gcur, const ull* __restrict__ ovf,
                       int* __restrict__ gcnt) {
    int nov = min(gcur[NBK], OVFCAP);
    for (int i = blockIdx.x * blockDim.x + threadIdx.x; i < nov; i += gridDim.x * blockDim.x) {
        int d = (int)(ovf[i] >> 32);
        atomicAdd(&gcnt[d], 1);
    }
}

__global__ void k_dinv(const int* __restrict__ gcnt, float* __restrict__ dinv) {
    int i = blockIdx.x * blockDim.x + threadIdx.x;
    if (i < NN) dinv[i] = rsqrtf((float)gcnt[i] + 1.0f);
}

// xp[s] = dinv[s]*x[s] padded to 16 floats (one aligned 64B line per row);
// second grid half zeroes aggovf.
__global__ void k_prep(const float* __restrict__ x, const float* __restrict__ dinv,
                       float* __restrict__ xp, float* __restrict__ aggovf) {
    int i = blockIdx.x * blockDim.x + threadIdx.x;
    if (i < NN * 16) {
        int node = i >> 4;
        int c = i & 15;
        xp[i] = (c < IC) ? dinv[node] * x[node * IC + c] : 0.0f;
    } else if (i < 2 * NN * 16) {
        aggovf[i - NN * 16] = 0.0f;
    }
}

__global__ void k_ovf2(const int* __restrict__ gcur, const ull* __restrict__ ovf,
                       const float* __restrict__ xp, float* __restrict__ aggovf) {
    int nov = min(gcur[NBK], OVFCAP);
    for (int i = blockIdx.x * blockDim.x + threadIdx.x; i < nov; i += gridDim.x * blockDim.x) {
        int d = (int)(ovf[i] >> 32);
        int s = (int)(ovf[i] & 0xFFFFFFFFu);
        for (int c = 0; c < 16; ++c)
            atomicAdd(&aggovf[(size_t)d * 16 + c], xp[(size_t)s * 16 + c]);
    }
}

// Layer-1 aggregation + node MLP. 4 lanes per dst node: lane q loads float4
// chunk q of each neighbor's 64B xp row -> one coalesced line request/edge.
// Partial sums cross lanes via LDS (stride 17, conflict-free), then threads
// 0..63 run the MLP for the block's 64 nodes.
__global__ __launch_bounds__(256) void k_agg1n(const int* __restrict__ rsg,
                                               const int* __restrict__ gcnt,
                                               const unsigned* __restrict__ csr,
                                               const float* __restrict__ xp,
                                               const float* __restrict__ aggovf,
                                               const float* __restrict__ dinv,
                                               const float* __restrict__ W1,
                                               const float* __restrict__ b1,
                                               const float* __restrict__ W2,
                                               const float* __restrict__ b2,
                                               float2* __restrict__ h2bp,
                                               float2* __restrict__ selfout) {
    __shared__ float sacc[64 * 17];
    __shared__ float sW1[IC * HC];
    __shared__ float sb1[HC];
    __shared__ float sW2[HC * OC];
    __shared__ float sb2[OC];
    int t = threadIdx.x;
    if (t < IC * HC) sW1[t] = W1[t];
    if (t < HC) sb1[t] = b1[t];
    if (t < HC * OC) sW2[t] = W2[t];
    if (t < OC) sb2[t] = b2[t];

    int g = t >> 2;            // group = node slot (0..63)
    int q = t & 3;             // chunk within row
    int i = blockIdx.x * 64 + g;  // 3125*64 == 200000 exactly
    int beg = rsg[i];
    int end = beg + gcnt[i];

    float ax = 0.0f, ay = 0.0f, az = 0.0f, aw = 0.0f;
    int j = beg;
    for (; j + 1 < end; j += 2) {  // 2 edges in flight
        int s0 = csr[j];
        int s1 = csr[j + 1];
        float4 u = *(const float4*)(xp + (size_t)s0 * 16 + 4 * q);
        float4 v = *(const float4*)(xp + (size_t)s1 * 16 + 4 * q);
        ax += u.x + v.x;
        ay += u.y + v.y;
        az += u.z + v.z;
        aw += u.w + v.w;
    }
    if (j < end) {
        float4 u = *(const float4*)(xp + (size_t)csr[j] * 16 + 4 * q);
        ax += u.x;
        ay += u.y;
        az += u.z;
        aw += u.w;
    }
    // self-loop (dinv^2*x == dinv*xp) + overflow fixup, own chunk
    float4 sp = *(const float4*)(xp + (size_t)i * 16 + 4 * q);
    float4 op = *(const float4*)(aggovf + (size_t)i * 16 + 4 * q);
    int sb_ = g * 17 + 4 * q;
    sacc[sb_ + 0] = ax + sp.x + op.x;
    sacc[sb_ + 1] = ay + sp.y + op.y;
    sacc[sb_ + 2] = az + sp.z + op.z;
    sacc[sb_ + 3] = aw + sp.w + op.w;
    __syncthreads();

    if (t < 64) {
        int i2 = blockIdx.x * 64 + t;
        float dv = dinv[i2];
        float tt[IC];
#pragma unroll
        for (int c = 0; c < IC; ++c) tt[c] = dv * sacc[t * 17 + c];

        float r[HC];
#pragma unroll
        for (int f = 0; f < HC; ++f) {
            float a = sb1[f];
#pragma unroll
            for (int c = 0; c < IC; ++c) a = fmaf(tt[c], sW1[c * HC + f], a);
            r[f] = fmaxf(a, 0.0f);
        }

        float o0 = 0.0f, o1 = 0.0f;
#pragma unroll
        for (int f = 0; f < HC; ++f) {
            o0 = fmaf(r[f], sW2[f * OC + 0], o0);
            o1 = fmaf(r[f], sW2[f * OC + 1], o1);
        }
        h2bp[i2] = make_float2(o0 * dv, o1 * dv);  // dinv-prescaled for layer 2
        selfout[i2] = make_float2(o0 * dv * dv + sb2[0], o1 * dv * dv + sb2[1]);
    }
}

// layer-2: out[i] = selfout[i] + dinv[i] * sum h2bp[src]; h2bp (1.6MB) L2-resident
__global__ __launch_bounds__(256) void k_agg2(const int* __restrict__ rsg,
                                              const int* __restrict__ gcnt,
                                              const unsigned* __restrict__ csr,
                                              const float* __restrict__ dinv,
                                              const float2* __restrict__ h2bp,
                                              const float2* __restrict__ selfout,
                                              float2* __restrict__ out) {
    int i = blockIdx.x * 256 + threadIdx.x;
    if (i >= NN) return;
    int beg = rsg[i];
    int end = beg + gcnt[i];
    float ax = 0.0f, ay = 0.0f;
    int j = beg;
    for (; j + 1 < end; j += 2) {
        float2 h0 = h2bp[csr[j]];
        float2 h1 = h2bp[csr[j + 1]];
        ax += h0.x + h1.x;
        ay += h0.y + h1.y;
    }
    if (j < end) {
        float2 h = h2bp[csr[j]];
        ax += h.x;
        ay += h.y;
    }
    float dv = dinv[i];
    float2 so = selfout[i];
    out[i] = make_float2(so.x + dv * ax, so.y + dv * ay);
}

__global__ void k_ovf3(const int* __restrict__ gcur, const ull* __restrict__ ovf,
                       const float* __restrict__ dinv, const float2* __restrict__ h2bp,
                       float* __restrict__ out) {
    int nov = min(gcur[NBK], OVFCAP);
    for (int i = blockIdx.x * blockDim.x + threadIdx.x; i < nov; i += gridDim.x * blockDim.x) {
        int d = (int)(ovf[i] >> 32);
        int s = (int)(ovf[i] & 0xFFFFFFFFu);
        float2 h = h2bp[s];
        atomicAdd(&out[(size_t)d * OC + 0], dinv[d] * h.x);
        atomicAdd(&out[(size_t)d * OC + 1], dinv[d] * h.y);
    }
}

extern "C" void kernel_launch(void* const* d_in, const int* in_sizes, int n_in,
                              void* d_out, int out_size, void* d_ws, size_t ws_size,
                              hipStream_t stream) {
    const float* x = (const float*)d_in[0];
    const void* ei = d_in[1];
    // d_in[2] = edge_attr (unused)
    const float* W1 = (const float*)d_in[3];
    const float* b1 = (const float*)d_in[4];
    const float* W2 = (const float*)d_in[5];
    const float* b2 = (const float*)d_in[6];
    float* out = (float*)d_out;

    ull* ovf = (ull*)d_ws;                              // OVFCAP
    int* gcur = (int*)(ovf + OVFCAP);                   // NBK+1 -> pad 512
    int* flag = gcur + 512;                             // 4
    int* gcnt = flag + 4;                               // NN
    int* rsg = gcnt + NN;                               // NN
    float* dinv = (float*)(rsg + NN);                   // NN
    float* xp = dinv + NN;                              // NN*16
    float* aggovf = xp + (size_t)NN * 16;               // NN*16
    float2* h2bp = (float2*)(aggovf + (size_t)NN * 16); // NN
    float2* selfout = h2bp + NN;                        // NN
    unsigned* binned = (unsigned*)(selfout + NN);       // NBK*CAP
    unsigned* csr = binned + (size_t)NBK * CAP;         // NBK*CAP

    k_flag<<<1, 64, 0, stream>>>(ei, flag);
    k_init<<<2, 256, 0, stream>>>(gcur);
    k_binA<<<NTILE, 256, 0, stream>>>(ei, flag, gcur, binned, ovf);
    k_sort<<<NBK, 512, 0, stream>>>(gcur, binned, csr, gcnt, rsg);
    k_ovf1<<<8, 256, 0, stream>>>(gcur, ovf, gcnt);
    k_dinv<<<NB, 256, 0, stream>>>(gcnt, dinv);
    k_prep<<<(2 * NN * 16 + 255) / 256, 256, 0, stream>>>(x, dinv, xp, aggovf);
    k_ovf2<<<8, 256, 0, stream>>>(gcur, ovf, xp, aggovf);
    k_agg1n<<<NN / 64, 256, 0, stream>>>(rsg, gcnt, csr, xp, aggovf, dinv, W1, b1, W2, b2,
                                         h2bp, selfout);
    k_agg2<<<NB, 256, 0, stream>>>(rsg, gcnt, csr, dinv, h2bp, selfout, (float2*)out);
    k_ovf3<<<8, 256, 0, stream>>>(gcur, ovf, dinv, h2bp, out);
}

// Round 7
// 483.910 us; speedup vs baseline: 2.0268x; 1.0557x over previous
//
#include <hip/hip_runtime.h>
#include <hip/hip_fp16.h>

// GCN 2-layer: N=200000, E=6400000, 14 -> 16(relu) -> 2.
// Round 7: R6's k_agg1n had ZERO L2 reuse (FETCH 552MB ~= E x 86B; xp 12.8MB
// >> 4MB/XCD L2) -> 3.4TB/s fabric-bound. Fixes:
//   - xp rows in fp16 (32B/row, 6.4MB total). Err budget ~5e-4 << 1.34e-3.
//   - src-range PHASED aggregation: grid = 2 x 3125; phase q touches only
//     srcs in [100k*q, 100k*(q+1)) -> 3.2MB gather region, L2-RESIDENT.
//     Phases write disjoint partial buffers (overlaid on dead `binned`
//     region; correctness independent of dispatch order). k_mlp sums
//     partials + self + ovf and runs the fused node MLP.
// Pipeline: binA (bin by dst>>9) -> sort (bucket counting sort; degrees free)
//   -> dinv/prep(fp16 xp) -> agg1 (2-phase filtered gather, reg acc) -> mlp
//   -> agg2 (layer-2 gather, h2bp L2-resident).

constexpr int NN = 200000;
constexpr int NE = 6400000;
constexpr int IC = 14;
constexpr int HC = 16;
constexpr int OC = 2;

constexpr int NBK = 392;                   // buckets of 512 dst nodes
constexpr int CAP = 18432;                 // mean 16328 + ~16 sigma
constexpr int TILE = 6400;
constexpr int IPT = TILE / 256;            // 25
constexpr int NTILE = NE / TILE;           // 1000
constexpr int OVFCAP = 65536;
constexpr int NB = (NN + 255) / 256;       // 782
constexpr int NAGG = NN / 64;              // 3125 blocks per phase

typedef unsigned long long ull;

__global__ void k_flag(const void* __restrict__ ei, int* __restrict__ flag) {
    if (blockIdx.x == 0 && threadIdx.x == 0) {
        const ull* p = (const ull*)ei;
        ull acc = 0ULL;
        for (int i = 0; i < 64; ++i) acc |= (p[i] >> 32);
        *flag = (acc == 0ULL) ? 1 : 0;  // 1 => int64 indices, 0 => int32
    }
}

__global__ void k_init(int* __restrict__ gcur) {
    int t = blockIdx.x * blockDim.x + threadIdx.x;
    if (t < NBK) gcur[t] = t * CAP;
    if (t == NBK) gcur[t] = 0;  // overflow counter
}

__device__ __forceinline__ int edge_src(const void* __restrict__ ei, int fl, int e) {
    if (fl) return (int)((const long long*)ei)[e];
    return ((const int*)ei)[e];
}
__device__ __forceinline__ int edge_dst(const void* __restrict__ ei, int fl, int e) {
    if (fl) return (int)((const long long*)ei)[NE + e];
    return ((const int*)ei)[NE + e];
}

__global__ __launch_bounds__(256) void k_binA(const void* __restrict__ ei,
                                              const int* __restrict__ flag,
                                              int* __restrict__ gcur,
                                              unsigned* __restrict__ binned,
                                              ull* __restrict__ ovf) {
    __shared__ int hist[NBK];       // per-bucket counts
    __shared__ int lofs[NBK];       // local exclusive offsets
    __shared__ int gofs[NBK];       // reserved global offsets
    __shared__ int scanbuf[256];
    __shared__ unsigned stage[TILE];
    __shared__ unsigned short sb[TILE];

    int t = threadIdx.x;
    int fl = *flag;
    int tile0 = blockIdx.x * TILE;

    if (t < NBK) hist[t] = 0;
    if (t + 256 < NBK) hist[t + 256] = 0;
    __syncthreads();

    // load dst; histogram atomic doubles as rank capture: dr = rank<<18 | dst
    int dr[IPT];
#pragma unroll
    for (int k = 0; k < IPT; ++k) {
        int e = tile0 + k * 256 + t;
        int d = edge_dst(ei, fl, e);
        int r = atomicAdd(&hist[d >> 9], 1);
        dr[k] = (r << 18) | d;
    }
    __syncthreads();

    // pairwise scan: 392 = 2*196 counts with a 256-wide Hillis-Steele
    int h0 = 0, h1 = 0, p = 0;
    if (t < NBK / 2) {
        h0 = hist[2 * t];
        h1 = hist[2 * t + 1];
        p = h0 + h1;
    }
    scanbuf[t] = p;
    __syncthreads();
#pragma unroll
    for (int off = 1; off < 256; off <<= 1) {
        int v = (t >= off) ? scanbuf[t - off] : 0;
        __syncthreads();
        scanbuf[t] += v;
        __syncthreads();
    }
    if (t < NBK / 2) {
        int excl = scanbuf[t] - p;
        lofs[2 * t] = excl;
        lofs[2 * t + 1] = excl + h0;
    }
    __syncthreads();
    if (t < NBK) gofs[t] = atomicAdd(&gcur[t], hist[t]);
    if (t + 256 < NBK) gofs[t + 256] = atomicAdd(&gcur[t + 256], hist[t + 256]);
    __syncthreads();

    // stage at lofs[bucket] + rank (no second atomic)
#pragma unroll
    for (int k = 0; k < IPT; ++k) {
        int e = tile0 + k * 256 + t;
        int s = edge_src(ei, fl, e);
        int d = dr[k] & 0x3FFFF;
        int r = ((unsigned)dr[k]) >> 18;
        int b = d >> 9;
        int pos = lofs[b] + r;
        stage[pos] = (unsigned)(((d & 511) << 18) | s);
        sb[pos] = (unsigned short)b;
    }
    __syncthreads();

    // coalesced write-out: consecutive i within a bucket -> consecutive dest
    for (int i = t; i < TILE; i += 256) {
        int b = sb[i];
        unsigned pack = stage[i];
        int dest = gofs[b] + (i - lofs[b]);
        if (dest < (b + 1) * CAP) {
            binned[dest] = pack;
        } else {  // overflow (never in practice)
            int op = atomicAdd(&gcur[NBK], 1);
            if (op < OVFCAP) {
                int d = (b << 9) | (int)(pack >> 18);
                int s = (int)(pack & 0x3FFFF);
                ovf[op] = ((ull)d << 32) | (unsigned)s;
            }
        }
    }
}

// bucket-local counting sort by dst; histogram doubles as degree output
__global__ __launch_bounds__(512) void k_sort(const int* __restrict__ gcur,
                                              const unsigned* __restrict__ binned,
                                              unsigned* __restrict__ csr,
                                              int* __restrict__ gcnt,
                                              int* __restrict__ rsg) {
    __shared__ int cnt[512];
    __shared__ int sh[512];
    __shared__ int cur[512];
    int b = blockIdx.x;
    int t = threadIdx.x;
    cnt[t] = 0;
    __syncthreads();
    int base = b * CAP;
    int n = min(gcur[b], (b + 1) * CAP) - base;
    for (int i = t; i < n; i += 512)
        atomicAdd(&cnt[binned[base + i] >> 18], 1);
    __syncthreads();
    int c = cnt[t];
    sh[t] = c;
    __syncthreads();
#pragma unroll
    for (int off = 1; off < 512; off <<= 1) {
        int v = (t >= off) ? sh[t - off] : 0;
        __syncthreads();
        sh[t] += v;
        __syncthreads();
    }
    int excl = sh[t] - c;
    cur[t] = base + excl;
    int g = (b << 9) + t;
    if (g < NN) {
        gcnt[g] = c;
        rsg[g] = base + excl;
    }
    __syncthreads();
    for (int i = t; i < n; i += 512) {
        unsigned pack = binned[base + i];
        int nl = (int)(pack >> 18);
        int pos = atomicAdd(&cur[nl], 1);
        csr[pos] = pack & 0x3FFFF;  // src only; dst implied by rsg ranges
    }
}

__global__ void k_ovf1(const int* __restrict__ gcur, const ull* __restrict__ ovf,
                       int* __restrict__ gcnt) {
    int nov = min(gcur[NBK], OVFCAP);
    for (int i = blockIdx.x * blockDim.x + threadIdx.x; i < nov; i += gridDim.x * blockDim.x) {
        int d = (int)(ovf[i] >> 32);
        atomicAdd(&gcnt[d], 1);
    }
}

__global__ void k_dinv(const int* __restrict__ gcnt, float* __restrict__ dinv) {
    int i = blockIdx.x * blockDim.x + threadIdx.x;
    if (i < NN) dinv[i] = rsqrtf((float)gcnt[i] + 1.0f);
}

// xph[s] = fp16(dinv[s]*x[s]) padded to 16 halves (32B row); also zero aggovf.
__global__ void k_prep(const float* __restrict__ x, const float* __restrict__ dinv,
                       __half* __restrict__ xph, float* __restrict__ aggovf) {
    int i = blockIdx.x * blockDim.x + threadIdx.x;
    if (i < NN * 16) {
        int node = i >> 4;
        int c = i & 15;
        float v = (c < IC) ? dinv[node] * x[node * IC + c] : 0.0f;
        xph[i] = __float2half(v);
    } else if (i < 2 * NN * 16) {
        aggovf[i - NN * 16] = 0.0f;
    }
}

__global__ void k_ovf2(const int* __restrict__ gcur, const ull* __restrict__ ovf,
                       const __half* __restrict__ xph, float* __restrict__ aggovf) {
    int nov = min(gcur[NBK], OVFCAP);
    for (int i = blockIdx.x * blockDim.x + threadIdx.x; i < nov; i += gridDim.x * blockDim.x) {
        int d = (int)(ovf[i] >> 32);
        int s = (int)(ovf[i] & 0xFFFFFFFFu);
        for (int c = 0; c < 16; ++c)
            atomicAdd(&aggovf[(size_t)d * 16 + c], __half2float(xph[(size_t)s * 16 + c]));
    }
}

// Layer-1 aggregation, src-range phased. Phase q (= blockIdx/3125) touches only
// srcs in [100000*q, 100000*(q+1)) -> 3.2MB fp16 region, L2-resident. 4 lanes
// per dst node, lane qq loads 8B (4 fp16 ch) of each matching neighbor row.
// Each phase writes its own partial buffer (no RMW, no cross-phase race).
__global__ __launch_bounds__(256) void k_agg1(const int* __restrict__ rsg,
                                              const int* __restrict__ gcnt,
                                              const unsigned* __restrict__ csr,
                                              const __half* __restrict__ xph,
                                              float* __restrict__ partial) {
    int t = threadIdx.x;
    int q = (blockIdx.x >= NAGG) ? 1 : 0;
    int blk = blockIdx.x - q * NAGG;
    int g = t >> 2;
    int qq = t & 3;
    int i = blk * 64 + g;
    int beg = rsg[i];
    int end = beg + gcnt[i];
    unsigned lo = (unsigned)(q * 100000);

    float ax = 0.0f, ay = 0.0f, az = 0.0f, aw = 0.0f;
    int j = beg;
    for (; j + 1 < end; j += 2) {
        int s0 = csr[j];
        int s1 = csr[j + 1];
        bool v0 = (unsigned)(s0 - lo) < 100000u;
        bool v1 = (unsigned)(s1 - lo) < 100000u;
        uint2 u0, u1;
        if (v0) u0 = *(const uint2*)(xph + (size_t)s0 * 16 + 4 * qq);
        if (v1) u1 = *(const uint2*)(xph + (size_t)s1 * 16 + 4 * qq);
        if (v0) {
            float2 f0 = __half22float2(*(__half2*)&u0.x);
            float2 f1 = __half22float2(*(__half2*)&u0.y);
            ax += f0.x; ay += f0.y; az += f1.x; aw += f1.y;
        }
        if (v1) {
            float2 f0 = __half22float2(*(__half2*)&u1.x);
            float2 f1 = __half22float2(*(__half2*)&u1.y);
            ax += f0.x; ay += f0.y; az += f1.x; aw += f1.y;
        }
    }
    if (j < end) {
        int s0 = csr[j];
        if ((unsigned)(s0 - lo) < 100000u) {
            uint2 u0 = *(const uint2*)(xph + (size_t)s0 * 16 + 4 * qq);
            float2 f0 = __half22float2(*(__half2*)&u0.x);
            float2 f1 = __half22float2(*(__half2*)&u0.y);
            ax += f0.x; ay += f0.y; az += f1.x; aw += f1.y;
        }
    }
    float4 r = {ax, ay, az, aw};
    *(float4*)(partial + ((size_t)q * NN + i) * 16 + 4 * qq) = r;
}

// Sum phase partials + self loop + ovf, then the fused node MLP.
__global__ __launch_bounds__(256) void k_mlp(const float* __restrict__ partial,
                                             const __half* __restrict__ xph,
                                             const float* __restrict__ aggovf,
                                             const float* __restrict__ dinv,
                                             const float* __restrict__ W1,
                                             const float* __restrict__ b1,
                                             const float* __restrict__ W2,
                                             const float* __restrict__ b2,
                                             float2* __restrict__ h2bp,
                                             float2* __restrict__ selfout) {
    __shared__ float sW1[IC * HC];
    __shared__ float sb1[HC];
    __shared__ float sW2[HC * OC];
    __shared__ float sb2[OC];
    int t = threadIdx.x;
    if (t < IC * HC) sW1[t] = W1[t];
    if (t < HC) sb1[t] = b1[t];
    if (t < HC * OC) sW2[t] = W2[t];
    if (t < OC) sb2[t] = b2[t];
    __syncthreads();

    int i = blockIdx.x * 256 + t;
    if (i >= NN) return;

    float dv = dinv[i];
    const float4* p0 = (const float4*)(partial + (size_t)i * 16);
    const float4* p1 = (const float4*)(partial + ((size_t)NN + i) * 16);
    const float4* ov = (const float4*)(aggovf + (size_t)i * 16);
    const uint2* sp = (const uint2*)(xph + (size_t)i * 16);

    float agg[16];
#pragma unroll
    for (int c4 = 0; c4 < 4; ++c4) {
        float4 a = p0[c4];
        float4 b = p1[c4];
        float4 o = ov[c4];
        uint2 u = sp[c4];
        float2 s0 = __half22float2(*(__half2*)&u.x);
        float2 s1 = __half22float2(*(__half2*)&u.y);
        agg[4 * c4 + 0] = a.x + b.x + o.x + s0.x;
        agg[4 * c4 + 1] = a.y + b.y + o.y + s0.y;
        agg[4 * c4 + 2] = a.z + b.z + o.z + s1.x;
        agg[4 * c4 + 3] = a.w + b.w + o.w + s1.y;
    }

    float tt[IC];
#pragma unroll
    for (int c = 0; c < IC; ++c) tt[c] = dv * agg[c];

    float r[HC];
#pragma unroll
    for (int f = 0; f < HC; ++f) {
        float a = sb1[f];
#pragma unroll
        for (int c = 0; c < IC; ++c) a = fmaf(tt[c], sW1[c * HC + f], a);
        r[f] = fmaxf(a, 0.0f);
    }

    float o0 = 0.0f, o1 = 0.0f;
#pragma unroll
    for (int f = 0; f < HC; ++f) {
        o0 = fmaf(r[f], sW2[f * OC + 0], o0);
        o1 = fmaf(r[f], sW2[f * OC + 1], o1);
    }
    h2bp[i] = make_float2(o0 * dv, o1 * dv);  // dinv-prescaled for layer 2
    selfout[i] = make_float2(o0 * dv * dv + sb2[0], o1 * dv * dv + sb2[1]);
}

// layer-2: out[i] = selfout[i] + dinv[i] * sum h2bp[src]; h2bp (1.6MB) L2-resident
__global__ __launch_bounds__(256) void k_agg2(const int* __restrict__ rsg,
                                              const int* __restrict__ gcnt,
                                              const unsigned* __restrict__ csr,
                                              const float* __restrict__ dinv,
                                              const float2* __restrict__ h2bp,
                                              const float2* __restrict__ selfout,
                                              float2* __restrict__ out) {
    int i = blockIdx.x * 256 + threadIdx.x;
    if (i >= NN) return;
    int beg = rsg[i];
    int end = beg + gcnt[i];
    float ax = 0.0f, ay = 0.0f;
    int j = beg;
    for (; j + 1 < end; j += 2) {
        float2 h0 = h2bp[csr[j]];
        float2 h1 = h2bp[csr[j + 1]];
        ax += h0.x + h1.x;
        ay += h0.y + h1.y;
    }
    if (j < end) {
        float2 h = h2bp[csr[j]];
        ax += h.x;
        ay += h.y;
    }
    float dv = dinv[i];
    float2 so = selfout[i];
    out[i] = make_float2(so.x + dv * ax, so.y + dv * ay);
}

__global__ void k_ovf3(const int* __restrict__ gcur, const ull* __restrict__ ovf,
                       const float* __restrict__ dinv, const float2* __restrict__ h2bp,
                       float* __restrict__ out) {
    int nov = min(gcur[NBK], OVFCAP);
    for (int i = blockIdx.x * blockDim.x + threadIdx.x; i < nov; i += gridDim.x * blockDim.x) {
        int d = (int)(ovf[i] >> 32);
        int s = (int)(ovf[i] & 0xFFFFFFFFu);
        float2 h = h2bp[s];
        atomicAdd(&out[(size_t)d * OC + 0], dinv[d] * h.x);
        atomicAdd(&out[(size_t)d * OC + 1], dinv[d] * h.y);
    }
}

extern "C" void kernel_launch(void* const* d_in, const int* in_sizes, int n_in,
                              void* d_out, int out_size, void* d_ws, size_t ws_size,
                              hipStream_t stream) {
    const float* x = (const float*)d_in[0];
    const void* ei = d_in[1];
    // d_in[2] = edge_attr (unused)
    const float* W1 = (const float*)d_in[3];
    const float* b1 = (const float*)d_in[4];
    const float* W2 = (const float*)d_in[5];
    const float* b2 = (const float*)d_in[6];
    float* out = (float*)d_out;

    ull* ovf = (ull*)d_ws;                              // OVFCAP       (0.5MB)
    int* gcur = (int*)(ovf + OVFCAP);                   // 512
    int* flag = gcur + 512;                             // 4
    int* gcnt = flag + 4;                               // NN
    int* rsg = gcnt + NN;                               // NN
    float* dinv = (float*)(rsg + NN);                   // NN
    __half* xph = (__half*)(dinv + NN);                 // NN*16 halves (6.4MB)
    float* aggovf = (float*)(xph + (size_t)NN * 16);    // NN*16        (12.8MB)
    float2* h2bp = (float2*)(aggovf + (size_t)NN * 16); // NN
    float2* selfout = h2bp + NN;                        // NN
    unsigned* binned = (unsigned*)(selfout + NN);       // NBK*CAP      (28.9MB)
    float* partial = (float*)binned;                    // 2*NN*16 f32 (25.6MB), overlays
                                                        // binned (dead after k_sort)
    unsigned* csr = binned + (size_t)NBK * CAP;         // NBK*CAP      (28.9MB)

    k_flag<<<1, 64, 0, stream>>>(ei, flag);
    k_init<<<2, 256, 0, stream>>>(gcur);
    k_binA<<<NTILE, 256, 0, stream>>>(ei, flag, gcur, binned, ovf);
    k_sort<<<NBK, 512, 0, stream>>>(gcur, binned, csr, gcnt, rsg);
    k_ovf1<<<8, 256, 0, stream>>>(gcur, ovf, gcnt);
    k_dinv<<<NB, 256, 0, stream>>>(gcnt, dinv);
    k_prep<<<(2 * NN * 16 + 255) / 256, 256, 0, stream>>>(x, dinv, xph, aggovf);
    k_ovf2<<<8, 256, 0, stream>>>(gcur, ovf, xph, aggovf);
    k_agg1<<<2 * NAGG, 256, 0, stream>>>(rsg, gcnt, csr, xph, partial);
    k_mlp<<<NB, 256, 0, stream>>>(partial, xph, aggovf, dinv, W1, b1, W2, b2, h2bp, selfout);
    k_agg2<<<NB, 256, 0, stream>>>(rsg, gcnt, csr, dinv, h2bp, selfout, (float2*)out);
    k_ovf3<<<8, 256, 0, stream>>>(gcur, ovf, dinv, h2bp, out);
}

// Round 8
// 418.812 us; speedup vs baseline: 2.3419x; 1.1554x over previous
//
#include <hip/hip_runtime.h>
#include <hip/hip_fp16.h>

// GCN 2-layer: N=200000, E=6400000, 14 -> 16(relu) -> 2.
// Round 8: exact phase partitioning + cheaper sort.
//   - k_sort: counting sort on key=(dlow<<1)|phase (1024 bins), phase = src>=100k.
//     csr is per-dst contiguous AND phase-partitioned (spl packs sub-counts).
//     Rank captured from the pass-1 histogram atomic -> NO cursor atomics in
//     pass 2 (halves the sort's 4cyc/lane LDS-atomic tax).
//   - k_agg1: phase q reads only its csr sub-range (csr once total, no filter
//     VALU); gather region 3.2MB fp16 -> L2-resident. 4-lane groups, 8B/lane.
//   - degree (gcnt, +ovf) now separate from csr ranges (rsg/spl) -> ovf-safe.
// Pipeline: binA -> sort -> dinv/prep -> agg1(2 phase) -> mlp -> agg2.

constexpr int NN = 200000;
constexpr int NE = 6400000;
constexpr int IC = 14;
constexpr int HC = 16;
constexpr int OC = 2;

constexpr int NBK = 392;                   // buckets of 512 dst nodes
constexpr int CAP = 18432;                 // mean 16328 + ~16 sigma; = 36*512
constexpr int SCH = CAP / 512;             // 36 sort chunks
constexpr int TILE = 6400;
constexpr int IPT = TILE / 256;            // 25
constexpr int NTILE = NE / TILE;           // 1000
constexpr int OVFCAP = 65536;
constexpr int NB = (NN + 255) / 256;       // 782
constexpr int NAGG = NN / 64;              // 3125 blocks per phase
constexpr unsigned PHB = 100000u;          // phase boundary on src

typedef unsigned long long ull;

__global__ void k_flag(const void* __restrict__ ei, int* __restrict__ flag) {
    if (blockIdx.x == 0 && threadIdx.x == 0) {
        const ull* p = (const ull*)ei;
        ull acc = 0ULL;
        for (int i = 0; i < 64; ++i) acc |= (p[i] >> 32);
        *flag = (acc == 0ULL) ? 1 : 0;  // 1 => int64 indices, 0 => int32
    }
}

__global__ void k_init(int* __restrict__ gcur) {
    int t = blockIdx.x * blockDim.x + threadIdx.x;
    if (t < NBK) gcur[t] = t * CAP;
    if (t == NBK) gcur[t] = 0;  // overflow counter
}

__device__ __forceinline__ int edge_src(const void* __restrict__ ei, int fl, int e) {
    if (fl) return (int)((const long long*)ei)[e];
    return ((const int*)ei)[e];
}
__device__ __forceinline__ int edge_dst(const void* __restrict__ ei, int fl, int e) {
    if (fl) return (int)((const long long*)ei)[NE + e];
    return ((const int*)ei)[NE + e];
}

__global__ __launch_bounds__(256) void k_binA(const void* __restrict__ ei,
                                              const int* __restrict__ flag,
                                              int* __restrict__ gcur,
                                              unsigned* __restrict__ binned,
                                              ull* __restrict__ ovf) {
    __shared__ int hist[NBK];       // per-bucket counts
    __shared__ int lofs[NBK];       // local exclusive offsets
    __shared__ int gofs[NBK];       // reserved global offsets
    __shared__ int scanbuf[256];
    __shared__ unsigned stage[TILE];
    __shared__ unsigned short sb[TILE];

    int t = threadIdx.x;
    int fl = *flag;
    int tile0 = blockIdx.x * TILE;

    if (t < NBK) hist[t] = 0;
    if (t + 256 < NBK) hist[t + 256] = 0;
    __syncthreads();

    // load dst; histogram atomic doubles as rank capture: dr = rank<<18 | dst
    int dr[IPT];
#pragma unroll
    for (int k = 0; k < IPT; ++k) {
        int e = tile0 + k * 256 + t;
        int d = edge_dst(ei, fl, e);
        int r = atomicAdd(&hist[d >> 9], 1);
        dr[k] = (r << 18) | d;
    }
    __syncthreads();

    // pairwise scan: 392 = 2*196 counts with a 256-wide Hillis-Steele
    int h0 = 0, h1 = 0, p = 0;
    if (t < NBK / 2) {
        h0 = hist[2 * t];
        h1 = hist[2 * t + 1];
        p = h0 + h1;
    }
    scanbuf[t] = p;
    __syncthreads();
#pragma unroll
    for (int off = 1; off < 256; off <<= 1) {
        int v = (t >= off) ? scanbuf[t - off] : 0;
        __syncthreads();
        scanbuf[t] += v;
        __syncthreads();
    }
    if (t < NBK / 2) {
        int excl = scanbuf[t] - p;
        lofs[2 * t] = excl;
        lofs[2 * t + 1] = excl + h0;
    }
    __syncthreads();
    if (t < NBK) gofs[t] = atomicAdd(&gcur[t], hist[t]);
    if (t + 256 < NBK) gofs[t + 256] = atomicAdd(&gcur[t + 256], hist[t + 256]);
    __syncthreads();

    // stage at lofs[bucket] + rank (no second atomic)
#pragma unroll
    for (int k = 0; k < IPT; ++k) {
        int e = tile0 + k * 256 + t;
        int s = edge_src(ei, fl, e);
        int d = dr[k] & 0x3FFFF;
        int r = ((unsigned)dr[k]) >> 18;
        int b = d >> 9;
        int pos = lofs[b] + r;
        stage[pos] = (unsigned)(((d & 511) << 18) | s);
        sb[pos] = (unsigned short)b;
    }
    __syncthreads();

    // coalesced write-out: consecutive i within a bucket -> consecutive dest
    for (int i = t; i < TILE; i += 256) {
        int b = sb[i];
        unsigned pack = stage[i];
        int dest = gofs[b] + (i - lofs[b]);
        if (dest < (b + 1) * CAP) {
            binned[dest] = pack;
        } else {  // overflow (never in practice)
            int op = atomicAdd(&gcur[NBK], 1);
            if (op < OVFCAP) {
                int d = (b << 9) | (int)(pack >> 18);
                int s = (int)(pack & 0x3FFFF);
                ovf[op] = ((ull)d << 32) | (unsigned)s;
            }
        }
    }
}

// bucket-local counting sort, key = (dlow<<1) | (src>=PHB).
// Pass 1 captures ranks from the histogram atomic; pass 2 scatters with NO
// atomics. Outputs: csr (src, per-dst contiguous + phase-partitioned),
// rsg (row start), spl (lo16=phase0 count, hi16=phase1 count), gcnt (degree).
__global__ __launch_bounds__(512) void k_sort(const int* __restrict__ gcur,
                                              const unsigned* __restrict__ binned,
                                              unsigned* __restrict__ csr,
                                              int* __restrict__ gcnt,
                                              int* __restrict__ rsg,
                                              unsigned* __restrict__ spl) {
    __shared__ int cnt[1024];
    __shared__ int excl[1024];
    __shared__ int scanbuf[512];
    int b = blockIdx.x;
    int t = threadIdx.x;
    cnt[t] = 0;
    cnt[t + 512] = 0;
    __syncthreads();
    int base = b * CAP;
    int n = min(gcur[b], (b + 1) * CAP) - base;

    unsigned short rank[SCH];
#pragma unroll
    for (int c = 0; c < SCH; ++c) {
        int i = c * 512 + t;
        if (i < n) {
            unsigned pack = binned[base + i];
            int key = ((int)(pack >> 18) << 1) | ((pack & 0x3FFFF) >= PHB ? 1 : 0);
            rank[c] = (unsigned short)atomicAdd(&cnt[key], 1);
        }
    }
    __syncthreads();

    // exclusive scan of 1024 counts: pairwise + 512-wide Hillis-Steele
    int c0 = cnt[2 * t];
    int c1 = cnt[2 * t + 1];
    int p = c0 + c1;
    scanbuf[t] = p;
    __syncthreads();
#pragma unroll
    for (int off = 1; off < 512; off <<= 1) {
        int v = (t >= off) ? scanbuf[t - off] : 0;
        __syncthreads();
        scanbuf[t] += v;
        __syncthreads();
    }
    int ex = scanbuf[t] - p;
    excl[2 * t] = ex;
    excl[2 * t + 1] = ex + c0;

    int g = (b << 9) + t;
    if (g < NN) {
        gcnt[g] = p;                                     // degree (ovf1 may add)
        rsg[g] = base + ex;                              // csr row start
        spl[g] = (unsigned)c0 | ((unsigned)c1 << 16);    // phase sub-counts
    }
    __syncthreads();

#pragma unroll
    for (int c = 0; c < SCH; ++c) {
        int i = c * 512 + t;
        if (i < n) {
            unsigned pack = binned[base + i];
            unsigned src = pack & 0x3FFFF;
            int key = ((int)(pack >> 18) << 1) | (src >= PHB ? 1 : 0);
            csr[base + excl[key] + rank[c]] = src;
        }
    }
}

__global__ void k_ovf1(const int* __restrict__ gcur, const ull* __restrict__ ovf,
                       int* __restrict__ gcnt) {
    int nov = min(gcur[NBK], OVFCAP);
    for (int i = blockIdx.x * blockDim.x + threadIdx.x; i < nov; i += gridDim.x * blockDim.x) {
        int d = (int)(ovf[i] >> 32);
        atomicAdd(&gcnt[d], 1);
    }
}

__global__ void k_dinv(const int* __restrict__ gcnt, float* __restrict__ dinv) {
    int i = blockIdx.x * blockDim.x + threadIdx.x;
    if (i < NN) dinv[i] = rsqrtf((float)gcnt[i] + 1.0f);
}

// xph[s] = fp16(dinv[s]*x[s]) padded to 16 halves (32B row); also zero aggovf.
__global__ void k_prep(const float* __restrict__ x, const float* __restrict__ dinv,
                       __half* __restrict__ xph, float* __restrict__ aggovf) {
    int i = blockIdx.x * blockDim.x + threadIdx.x;
    if (i < NN * 16) {
        int node = i >> 4;
        int c = i & 15;
        float v = (c < IC) ? dinv[node] * x[node * IC + c] : 0.0f;
        xph[i] = __float2half(v);
    } else if (i < 2 * NN * 16) {
        aggovf[i - NN * 16] = 0.0f;
    }
}

__global__ void k_ovf2(const int* __restrict__ gcur, const ull* __restrict__ ovf,
                       const __half* __restrict__ xph, float* __restrict__ aggovf) {
    int nov = min(gcur[NBK], OVFCAP);
    for (int i = blockIdx.x * blockDim.x + threadIdx.x; i < nov; i += gridDim.x * blockDim.x) {
        int d = (int)(ovf[i] >> 32);
        int s = (int)(ovf[i] & 0xFFFFFFFFu);
        for (int c = 0; c < 16; ++c)
            atomicAdd(&aggovf[(size_t)d * 16 + c], __half2float(xph[(size_t)s * 16 + c]));
    }
}

// Layer-1 aggregation. Phase q reads ONLY its csr sub-range (exact partition,
// no filtering). Gather region = 3.2MB fp16, L2-resident. 4 lanes per dst
// node; lane qq loads 8B (4 fp16 ch) of each neighbor row.
__global__ __launch_bounds__(256) void k_agg1(const int* __restrict__ rsg,
                                              const unsigned* __restrict__ spl,
                                              const unsigned* __restrict__ csr,
                                              const __half* __restrict__ xph,
                                              float* __restrict__ partial) {
    int t = threadIdx.x;
    int q = (blockIdx.x >= NAGG) ? 1 : 0;
    int blk = blockIdx.x - q * NAGG;
    int g = t >> 2;
    int qq = t & 3;
    int i = blk * 64 + g;
    unsigned sp = spl[i];
    int n0 = (int)(sp & 0xFFFF);
    int n1 = (int)(sp >> 16);
    int beg = rsg[i] + (q ? n0 : 0);
    int end = beg + (q ? n1 : n0);

    float ax = 0.0f, ay = 0.0f, az = 0.0f, aw = 0.0f;
    int j = beg;
    for (; j + 1 < end; j += 2) {
        int s0 = csr[j];
        int s1 = csr[j + 1];
        uint2 u0 = *(const uint2*)(xph + (size_t)s0 * 16 + 4 * qq);
        uint2 u1 = *(const uint2*)(xph + (size_t)s1 * 16 + 4 * qq);
        float2 f0 = __half22float2(*(__half2*)&u0.x);
        float2 f1 = __half22float2(*(__half2*)&u0.y);
        float2 f2 = __half22float2(*(__half2*)&u1.x);
        float2 f3 = __half22float2(*(__half2*)&u1.y);
        ax += f0.x + f2.x;
        ay += f0.y + f2.y;
        az += f1.x + f3.x;
        aw += f1.y + f3.y;
    }
    if (j < end) {
        uint2 u0 = *(const uint2*)(xph + (size_t)csr[j] * 16 + 4 * qq);
        float2 f0 = __half22float2(*(__half2*)&u0.x);
        float2 f1 = __half22float2(*(__half2*)&u0.y);
        ax += f0.x;
        ay += f0.y;
        az += f1.x;
        aw += f1.y;
    }
    float4 r = {ax, ay, az, aw};
    *(float4*)(partial + ((size_t)q * NN + i) * 16 + 4 * qq) = r;
}

// Sum phase partials + self loop + ovf, then the fused node MLP.
__global__ __launch_bounds__(256) void k_mlp(const float* __restrict__ partial,
                                             const __half* __restrict__ xph,
                                             const float* __restrict__ aggovf,
                                             const float* __restrict__ dinv,
                                             const float* __restrict__ W1,
                                             const float* __restrict__ b1,
                                             const float* __restrict__ W2,
                                             const float* __restrict__ b2,
                                             float2* __restrict__ h2bp,
                                             float2* __restrict__ selfout) {
    __shared__ float sW1[IC * HC];
    __shared__ float sb1[HC];
    __shared__ float sW2[HC * OC];
    __shared__ float sb2[OC];
    int t = threadIdx.x;
    if (t < IC * HC) sW1[t] = W1[t];
    if (t < HC) sb1[t] = b1[t];
    if (t < HC * OC) sW2[t] = W2[t];
    if (t < OC) sb2[t] = b2[t];
    __syncthreads();

    int i = blockIdx.x * 256 + t;
    if (i >= NN) return;

    float dv = dinv[i];
    const float4* p0 = (const float4*)(partial + (size_t)i * 16);
    const float4* p1 = (const float4*)(partial + ((size_t)NN + i) * 16);
    const float4* ov = (const float4*)(aggovf + (size_t)i * 16);
    const uint2* sp = (const uint2*)(xph + (size_t)i * 16);

    float agg[16];
#pragma unroll
    for (int c4 = 0; c4 < 4; ++c4) {
        float4 a = p0[c4];
        float4 b = p1[c4];
        float4 o = ov[c4];
        uint2 u = sp[c4];
        float2 s0 = __half22float2(*(__half2*)&u.x);
        float2 s1 = __half22float2(*(__half2*)&u.y);
        agg[4 * c4 + 0] = a.x + b.x + o.x + s0.x;
        agg[4 * c4 + 1] = a.y + b.y + o.y + s0.y;
        agg[4 * c4 + 2] = a.z + b.z + o.z + s1.x;
        agg[4 * c4 + 3] = a.w + b.w + o.w + s1.y;
    }

    float tt[IC];
#pragma unroll
    for (int c = 0; c < IC; ++c) tt[c] = dv * agg[c];

    float r[HC];
#pragma unroll
    for (int f = 0; f < HC; ++f) {
        float a = sb1[f];
#pragma unroll
        for (int c = 0; c < IC; ++c) a = fmaf(tt[c], sW1[c * HC + f], a);
        r[f] = fmaxf(a, 0.0f);
    }

    float o0 = 0.0f, o1 = 0.0f;
#pragma unroll
    for (int f = 0; f < HC; ++f) {
        o0 = fmaf(r[f], sW2[f * OC + 0], o0);
        o1 = fmaf(r[f], sW2[f * OC + 1], o1);
    }
    h2bp[i] = make_float2(o0 * dv, o1 * dv);  // dinv-prescaled for layer 2
    selfout[i] = make_float2(o0 * dv * dv + sb2[0], o1 * dv * dv + sb2[1]);
}

// layer-2: out[i] = selfout[i] + dinv[i] * sum h2bp[src]; h2bp (1.6MB) L2-resident
__global__ __launch_bounds__(256) void k_agg2(const int* __restrict__ rsg,
                                              const unsigned* __restrict__ spl,
                                              const unsigned* __restrict__ csr,
                                              const float* __restrict__ dinv,
                                              const float2* __restrict__ h2bp,
                                              const float2* __restrict__ selfout,
                                              float2* __restrict__ out) {
    int i = blockIdx.x * 256 + threadIdx.x;
    if (i >= NN) return;
    unsigned sp = spl[i];
    int beg = rsg[i];
    int end = beg + (int)(sp & 0xFFFF) + (int)(sp >> 16);
    float ax = 0.0f, ay = 0.0f;
    int j = beg;
    for (; j + 3 < end; j += 4) {
        float2 h0 = h2bp[csr[j]];
        float2 h1 = h2bp[csr[j + 1]];
        float2 h2 = h2bp[csr[j + 2]];
        float2 h3 = h2bp[csr[j + 3]];
        ax += (h0.x + h1.x) + (h2.x + h3.x);
        ay += (h0.y + h1.y) + (h2.y + h3.y);
    }
    for (; j < end; ++j) {
        float2 h = h2bp[csr[j]];
        ax += h.x;
        ay += h.y;
    }
    float dv = dinv[i];
    float2 so = selfout[i];
    out[i] = make_float2(so.x + dv * ax, so.y + dv * ay);
}

__global__ void k_ovf3(const int* __restrict__ gcur, const ull* __restrict__ ovf,
                       const float* __restrict__ dinv, const float2* __restrict__ h2bp,
                       float* __restrict__ out) {
    int nov = min(gcur[NBK], OVFCAP);
    for (int i = blockIdx.x * blockDim.x + threadIdx.x; i < nov; i += gridDim.x * blockDim.x) {
        int d = (int)(ovf[i] >> 32);
        int s = (int)(ovf[i] & 0xFFFFFFFFu);
        float2 h = h2bp[s];
        atomicAdd(&out[(size_t)d * OC + 0], dinv[d] * h.x);
        atomicAdd(&out[(size_t)d * OC + 1], dinv[d] * h.y);
    }
}

extern "C" void kernel_launch(void* const* d_in, const int* in_sizes, int n_in,
                              void* d_out, int out_size, void* d_ws, size_t ws_size,
                              hipStream_t stream) {
    const float* x = (const float*)d_in[0];
    const void* ei = d_in[1];
    // d_in[2] = edge_attr (unused)
    const float* W1 = (const float*)d_in[3];
    const float* b1 = (const float*)d_in[4];
    const float* W2 = (const float*)d_in[5];
    const float* b2 = (const float*)d_in[6];
    float* out = (float*)d_out;

    ull* ovf = (ull*)d_ws;                              // OVFCAP       (0.5MB)
    int* gcur = (int*)(ovf + OVFCAP);                   // 512
    int* flag = gcur + 512;                             // 4
    int* gcnt = flag + 4;                               // NN
    int* rsg = gcnt + NN;                               // NN
    unsigned* spl = (unsigned*)(rsg + NN);              // NN
    float* dinv = (float*)(spl + NN);                   // NN
    __half* xph = (__half*)(dinv + NN);                 // NN*16 halves (6.4MB)
    float* aggovf = (float*)(xph + (size_t)NN * 16);    // NN*16        (12.8MB)
    float2* h2bp = (float2*)(aggovf + (size_t)NN * 16); // NN
    float2* selfout = h2bp + NN;                        // NN
    unsigned* binned = (unsigned*)(selfout + NN);       // NBK*CAP      (28.9MB)
    float* partial = (float*)binned;                    // 2*NN*16 f32 (25.6MB), overlays
                                                        // binned (dead after k_sort)
    unsigned* csr = binned + (size_t)NBK * CAP;         // NBK*CAP      (28.9MB)

    k_flag<<<1, 64, 0, stream>>>(ei, flag);
    k_init<<<2, 256, 0, stream>>>(gcur);
    k_binA<<<NTILE, 256, 0, stream>>>(ei, flag, gcur, binned, ovf);
    k_sort<<<NBK, 512, 0, stream>>>(gcur, binned, csr, gcnt, rsg, spl);
    k_ovf1<<<8, 256, 0, stream>>>(gcur, ovf, gcnt);
    k_dinv<<<NB, 256, 0, stream>>>(gcnt, dinv);
    k_prep<<<(2 * NN * 16 + 255) / 256, 256, 0, stream>>>(x, dinv, xph, aggovf);
    k_ovf2<<<8, 256, 0, stream>>>(gcur, ovf, xph, aggovf);
    k_agg1<<<2 * NAGG, 256, 0, stream>>>(rsg, spl, csr, xph, partial);
    k_mlp<<<NB, 256, 0, stream>>>(partial, xph, aggovf, dinv, W1, b1, W2, b2, h2bp, selfout);
    k_agg2<<<NB, 256, 0, stream>>>(rsg, spl, csr, dinv, h2bp, selfout, (float2*)out);
    k_ovf3<<<8, 256, 0, stream>>>(gcur, ovf, dinv, h2bp, out);
}